// Round 11
// baseline (149.033 us; speedup 1.0000x reference)
//
#include <hip/hip_runtime.h>
#include <stdint.h>

#define T_STEPS 2048
#define BB 64
#define CC 128
#define HH 256
#define NCLS 10

// ws layout:
//   s1b dwords [T][B][4]    : 2048*64*16 = 2097152 B (layer-1 spike BITS:
//                             bit j of dword d -> c = d*32+j)
//   dp  i8   [4][H][C]      : 4*256*128  =  131072 B (W1 digit planes)
//   dp2 i8   [4][16][256]   : 4*16*256   =   16384 B (W2 digit planes, nc padded)
//   s2w dwords [T][B][8]    : 2048*64*32 = 4194304 B (layer-2 spike BITS: bit j
//                             of dword d -> h = d*32+j)
// k2/k34 prefetch overruns land in the region following each buffer (dp after
// s1b; ws slack after s2w) -- loads only, values never consumed.
#define S1_OFF  0
#define DP_OFF  2097152
#define DP2_OFF 2228224
#define S2W_OFF 2244608

typedef int v4i __attribute__((ext_vector_type(4)));

// 16 spike bits -> 16 i8 bytes (0/1), as one MFMA A-fragment v4i.
__device__ __forceinline__ v4i spread16(unsigned h) {
  v4i a;
  a[0] = (int)((((h      ) & 0xFu) * 0x00204081u) & 0x01010101u);
  a[1] = (int)((((h >> 4 ) & 0xFu) * 0x00204081u) & 0x01010101u);
  a[2] = (int)((((h >> 8 ) & 0xFu) * 0x00204081u) & 0x01010101u);
  a[3] = (int)((((h >> 12) & 0xFu) * 0x00204081u) & 0x01010101u);
  return a;
}

// ---------------- K01: digits + conv/LIF1(bits) + out-zero, one dispatch ------
// blocks 0..1023   : conv1d+LIF1, chunk = bx>>6, b = bx&63 (128 steps, 64 warmup)
//                    x-window (199 floats) staged in LDS once per block [R8: -14us]
// blocks 1024..1279: W1 digit planes, h = bx-1024
// blocks 1280..1295: W2 digit planes, nc = bx-1280 (rows >= NCLS zeroed)
// block  1296      : zero d_out (re-poisoned 0xAA before every call)
__global__ __launch_bounds__(128) void k01_prep(
    const float* __restrict__ x, const float* __restrict__ cw,
    const float* __restrict__ W1, const float* __restrict__ W2,
    unsigned int* __restrict__ s1b, signed char* __restrict__ dp,
    signed char* __restrict__ dp2, float* __restrict__ out) {
  const int bx = blockIdx.x;
  const int tidx = threadIdx.x;
  __shared__ float xs[200];

  if (bx < 1024) {
    const int c = tidx;
    const int wv = tidx >> 6;       // 0..1 -> dwords 2*wv, 2*wv+1
    const int lane = tidx & 63;
    const int b = bx & 63;
    const int t0 = (bx >> 6) * 128;
    const int ts = t0 - 64;

    // stage x[t0-67 .. t0+131] (199 floats; OOB -> 0) -- coalesced, once.
    const float* xb = x + b * 2048;
    const int base = t0 - 67;
    for (int i = tidx; i < 200; i += 128) {
      int l = base + i;
      xs[i] = (l >= 0 && l < 2048) ? xb[l] : 0.0f;
    }
    __syncthreads();

    float w[7];
#pragma unroll
    for (int k = 0; k < 7; ++k) w[k] = cw[c * 7 + k];

    float xw[7];
#pragma unroll
    for (int k = 0; k < 7; ++k) xw[k] = xs[k];   // l = ts+k-3 = base+k

    float v = 0.0f;
#pragma unroll 7
    for (int t = ts; t < t0 + 128; ++t) {
      float u = fmaf(w[0], xw[0],
                fmaf(w[1], xw[1],
                fmaf(w[2], xw[2],
                fmaf(w[3], xw[3],
                fmaf(w[4], xw[4],
                fmaf(w[5], xw[5], w[6] * xw[6]))))));
      v = fmaf(v, 0.5f, u);           // v*0.5 exact -> fmaf == ref's mul-then-add
      bool sp = (v >= 1.0f);
      unsigned long long Bm = __ballot(sp);   // bit i -> c = wv*64 + i
      if (t >= t0 && lane == 0)
        *(unsigned long long*)(s1b + ((size_t)t * BB + b) * 4 + wv * 2) = Bm;
      if (sp) v = 0.0f;
#pragma unroll
      for (int k = 0; k < 6; ++k) xw[k] = xw[k + 1];
      xw[6] = xs[t - t0 + 71];        // l = t+4 = base + (t-t0+71); OOB staged 0
    }
  } else if (bx < 1280) {
    // W1 digits: q = rn(w*2^31), q = d0 + 256*(d1 + 256*(d2 + 256*d3)), exact.
    const int h = bx - 1024;
    const int c = tidx;
    float w = W1[h * CC + c];
    int q = __float2int_rn(w * 2147483648.0f);
#pragma unroll
    for (int d = 0; d < 3; ++d) {
      int dig = (int)(signed char)(q & 0xff);
      dp[d * (HH * CC) + h * CC + c] = (signed char)dig;
      q = (q - dig) >> 8;
    }
    dp[3 * (HH * CC) + h * CC + c] = (signed char)q;
  } else if (bx < 1296) {
    const int nc = bx - 1280;       // 0..15
#pragma unroll
    for (int half = 0; half < 2; ++half) {
      int cc = half * 128 + tidx;
      float w = (nc < NCLS) ? W2[nc * HH + cc] : 0.0f;
      int q = __float2int_rn(w * 2147483648.0f);
#pragma unroll
      for (int d = 0; d < 3; ++d) {
        int dig = (int)(signed char)(q & 0xff);
        dp2[d * (16 * HH) + nc * HH + cc] = (signed char)dig;
        q = (q - dig) >> 8;
      }
      dp2[3 * (16 * HH) + nc * HH + cc] = (signed char)q;
    }
  } else {
#pragma unroll
    for (int i = 0; i < 5; ++i) out[tidx + 128 * i] = 0.0f;   // 640 = 5*128
  }
}

// ---------------- K2: fused MFMA-i8 (s1bits @ W1^T) + LIF2 -> s2 BITS ----------
// [R11: revert to R8 32-h structure (64-h cost +4%, R10); DECOUPLED LIF/pack]
// grid (2 hg, 64 b, 8 chunks), block 256 (4 waves); wave owns 32 h
// (n-tiles n=0,1: h = hg*128 + wv*32 + n*16 + l15). t-chunk = 256 steps
// (+64 warmup for chunk>0; exact: decay 2^-64 + hard reset).
// Evidence trail: VALU cuts neutral (R6), TLP halved costs only 4% (R10) ->
// bottleneck theory = the 16-step LIF recurrence with a ballot PER STEP:
// fmaf -> v_cmp(SGPR write) -> VALU read of ballot SGPR -> pack, a serial
// cross-domain round-trip 16 deep. R11 splits it: (a) pure in-lane LIF
// (fmaf/cmp/reset/sbits|=1<<j, vcc-masked only, no SGPR data reads);
// (b) 16 INDEPENDENT ballots of (sbits>>j)&1 that pipeline, SALU pack,
// l15==j cndmask deposit (pure C, no asm). Pack loop skipped in warmup subs.
// Per 16-t sub: 16 x mfma_i32_16x16x64_i8 (2n x 2kc x 4 digits), ZERO C on
// first of each chain, exact digit recombine, bpermute transpose; lg-pairs own
// n (nn = lg>>1) so each lane scans ONE 16-step LIF column in-lane.
__global__ __launch_bounds__(256, 4) void k2_mfma_lif2(
    const unsigned int* __restrict__ s1b, const signed char* __restrict__ dp,
    unsigned int* __restrict__ s2w) {
  const int tid  = threadIdx.x;
  const int lane = tid & 63;
  const int wv   = tid >> 6;        // 0..3
  const int hg   = blockIdx.x;      // 0..1
  const int b    = blockIdx.y;      // 0..63
  const int chunk= blockIdx.z;      // 0..7
  const int t0   = chunk * 256;
  const int nwarm= (chunk == 0) ? 0 : 4;      // warmup sub-chunks (x16 t)
  const int ts   = t0 - nwarm * 16;
  const int l15  = lane & 15;
  const int lg   = lane >> 4;       // 0..3
  const int nn   = lg >> 1;         // this lane's owned n-tile
  const int hb   = hg * 128 + wv * 32;
  const int hw   = (lg & 1) * 16;   // halfword shift within bit-row dword

  // B fragments (verified layout): lane holds k = kc*64 + lg*16 + j.
  v4i Bf[2][4][2];
#pragma unroll
  for (int n = 0; n < 2; ++n)
#pragma unroll
    for (int d = 0; d < 4; ++d)
#pragma unroll
      for (int kc = 0; kc < 2; ++kc)
        Bf[n][d][kc] = *(const v4i*)(dp + d * (HH * CC) +
                                     (hb + n * 16 + l15) * CC + kc * 64 + lg * 16);

  // A bit-rows: lane reads row t = tb + l15 (16B = 128 c-bits), 2-deep prefetch.
  const unsigned int* ap = s1b + ((size_t)(ts + l15) * BB + b) * 4;
  uint4 Ra = *(const uint4*)ap;
  uint4 Pb = *(const uint4*)(ap + 16 * BB * 4);
  const unsigned int* ap2 = ap + 2 * 16 * BB * 4;

  const int a4 = l15 * 4;           // bpermute byte-addr base
  float v = 0.0f;                   // LIF2 state for column (h = hb + nn*16 + l15)
  const v4i ZZ = {0, 0, 0, 0};      // loop-invariant zero C operand

  const int nsub = nwarm + 16;
  for (int s = 0; s < nsub; ++s) {
    const int tb = ts + s * 16;

    // prefetch sub s+2 (overrun past s1b lands in dp region: loads-only)
    uint4 Pc = *(const uint4*)ap2;
    ap2 += 16 * BB * 4;

    // decode this sub's A fragments from bits (same nibble-spread as k34)
    const unsigned w01 = (lg & 2) ? Ra.y : Ra.x;   // kc=0 dword (lg>>1)
    const unsigned w23 = (lg & 2) ? Ra.w : Ra.z;   // kc=1 dword 2+(lg>>1)
    v4i Af0 = spread16((w01 >> hw) & 0xFFFFu);
    v4i Af1 = spread16((w23 >> hw) & 0xFFFFu);

    float u0[4], u1[4];
#pragma unroll
    for (int n = 0; n < 2; ++n) {
      v4i a0, a1, a2, a3;
      a0 = __builtin_amdgcn_mfma_i32_16x16x64_i8(Af0, Bf[n][0][0], ZZ, 0, 0, 0);
      a1 = __builtin_amdgcn_mfma_i32_16x16x64_i8(Af0, Bf[n][1][0], ZZ, 0, 0, 0);
      a2 = __builtin_amdgcn_mfma_i32_16x16x64_i8(Af0, Bf[n][2][0], ZZ, 0, 0, 0);
      a3 = __builtin_amdgcn_mfma_i32_16x16x64_i8(Af0, Bf[n][3][0], ZZ, 0, 0, 0);
      a0 = __builtin_amdgcn_mfma_i32_16x16x64_i8(Af1, Bf[n][0][1], a0, 0, 0, 0);
      a1 = __builtin_amdgcn_mfma_i32_16x16x64_i8(Af1, Bf[n][1][1], a1, 0, 0, 0);
      a2 = __builtin_amdgcn_mfma_i32_16x16x64_i8(Af1, Bf[n][2][1], a2, 0, 0, 0);
      a3 = __builtin_amdgcn_mfma_i32_16x16x64_i8(Af1, Bf[n][3][1], a3, 0, 0, 0);
#pragma unroll
      for (int r = 0; r < 4; ++r) {
        int hi = a3[r] * 256 + a2[r];             // exact, |.| < 2^24
        int lo = a1[r] * 256 + a0[r];
        float u = fmaf((float)hi, 0x1p-15f, (float)lo * 0x1p-31f);
        if (n == 0) u0[r] = u; else u1[r] = u;
      }
    }

    // transpose: lane gathers the full 16-row t-column of its (nn, l15)
    float ua[16];
#pragma unroll
    for (int q = 0; q < 4; ++q) {
      const int addr = a4 + q * 64;
#pragma unroll
      for (int r = 0; r < 4; ++r) {
        int g0 = __builtin_amdgcn_ds_bpermute(addr, __float_as_int(u0[r]));
        int g1 = __builtin_amdgcn_ds_bpermute(addr, __float_as_int(u1[r]));
        ua[q * 4 + r] = __int_as_float(nn ? g1 : g0);
      }
    }

    // (a) pure in-lane 16-step LIF: no cross-lane ops in the recurrence.
    unsigned sbits = 0;
#pragma unroll
    for (int j = 0; j < 16; ++j) {
      v = fmaf(v, 0.5f, ua[j]);
      bool sp = (v >= 1.0f);
      if (sp) { v = 0.0f; sbits |= (1u << j); }
    }

    // (b) 16 independent ballots (pipeline freely), SALU pack, cndmask deposit.
    // ballot bit i = lane i's column spike at step j; lanes 0-15 = h hb+0..15,
    // lanes 32-47 = h hb+16..31 (lg1/lg3 are duplicates, masked out) -- same
    // pack expression as the R2/R8-verified kernels.
    if (s >= nwarm) {
      unsigned sel = 0;
#pragma unroll
      for (int j = 0; j < 16; ++j) {
        unsigned long long Bm = __ballot(((sbits >> j) & 1u) != 0);
        unsigned pk = (unsigned)(Bm & 0xFFFFull) |
                      ((unsigned)((Bm >> 32) & 0xFFFFull) << 16);
        if (l15 == j) sel = pk;
      }
      if (lg == 0)                  // 16 lanes store dword(32 h) for t = tb+l15
        s2w[((size_t)(tb + l15) * BB + b) * 8 + hg * 4 + wv] = sel;
    }

    Ra = Pb; Pb = Pc;
  }
}

// ---------------- K34: fused MFMA-i8 (s2bits @ W2^T) + LIF3 + count ------------
// grid (64 b, 64 chunks), block 64 (1 wave); 4096 waves = 4/SIMD.
// chunk = 32 t = 2 subs (+4 warmup subs, chunk>0). Per sub: load the 16 t-rows'
// 256-bit spike bitmaps (2 dwordx4/lane), nibble-spread decode to i8 A-frags,
// 16 MFMA (4 kc x 4 digits, ZERO C on first of each chain), exact recombine,
// bpermute transpose, in-lane LIF3 + spike count; one atomicAdd per class.
__global__ __launch_bounds__(64, 4) void k34_gemm3_lif3(
    const unsigned int* __restrict__ s2w, const signed char* __restrict__ dp2,
    float* __restrict__ out) {
  const int lane = threadIdx.x;
  const int l15  = lane & 15;
  const int lg   = lane >> 4;
  const int b    = blockIdx.x;      // 0..63
  const int chunk= blockIdx.y;      // 0..63
  const int t0   = chunk * 32;
  const int nwarm= (chunk == 0) ? 0 : 4;
  const int ts   = t0 - nwarm * 16;

  v4i Bf[4][4];                     // [digit][kc]; col = l15 -> nc
#pragma unroll
  for (int d = 0; d < 4; ++d)
#pragma unroll
    for (int kc = 0; kc < 4; ++kc)
      Bf[d][kc] = *(const v4i*)(dp2 + d * (16 * HH) + l15 * HH + kc * 64 + lg * 16);

  // bit-row pointer for t = ts + l15 (row = 8 dwords = 2 uint4)
  const uint4* rp = (const uint4*)s2w + ((size_t)(ts + l15) * BB + b) * 2;
  uint4 r0 = rp[0], r1 = rp[1];
  rp += 16 * BB * 2;

  const int a4 = l15 * 4;
  const int hw = (lg & 1) * 16;     // halfword shift
  float v = 0.0f, cnt = 0.0f;
  const v4i ZZ = {0, 0, 0, 0};      // loop-invariant zero C operand

  const int nsub = nwarm + 2;
  for (int s = 0; s < nsub; ++s) {
    uint4 p0 = rp[0], p1 = rp[1];   // prefetch (overrun past s2w: slack ws)
    rp += 16 * BB * 2;

    unsigned rowd[8] = {r0.x, r0.y, r0.z, r0.w, r1.x, r1.y, r1.z, r1.w};

    v4i a0, a1, a2, a3;
#pragma unroll
    for (int kc = 0; kc < 4; ++kc) {
      unsigned h16 = (rowd[kc * 2 + (lg >> 1)] >> hw) & 0xFFFFu;
      v4i Af = spread16(h16);
      a0 = __builtin_amdgcn_mfma_i32_16x16x64_i8(Af, Bf[0][kc], kc ? a0 : ZZ, 0, 0, 0);
      a1 = __builtin_amdgcn_mfma_i32_16x16x64_i8(Af, Bf[1][kc], kc ? a1 : ZZ, 0, 0, 0);
      a2 = __builtin_amdgcn_mfma_i32_16x16x64_i8(Af, Bf[2][kc], kc ? a2 : ZZ, 0, 0, 0);
      a3 = __builtin_amdgcn_mfma_i32_16x16x64_i8(Af, Bf[3][kc], kc ? a3 : ZZ, 0, 0, 0);
    }

    float u[4];
#pragma unroll
    for (int r = 0; r < 4; ++r) {
      int hi = a3[r] * 256 + a2[r];
      int lo = a1[r] * 256 + a0[r];
      u[r] = fmaf((float)hi, 0x1p-15f, (float)lo * 0x1p-31f);
    }

    float ua[16];
#pragma unroll
    for (int q = 0; q < 4; ++q) {
      const int addr = a4 + q * 64;
#pragma unroll
      for (int r = 0; r < 4; ++r)
        ua[q * 4 + r] = __int_as_float(
            __builtin_amdgcn_ds_bpermute(addr, __float_as_int(u[r])));
    }

    float inc = (s >= nwarm) ? 1.0f : 0.0f;
#pragma unroll
    for (int j = 0; j < 16; ++j) {
      v = fmaf(v, 0.5f, ua[j]);
      bool sp = (v >= 1.0f);
      if (sp) { v = 0.0f; cnt += inc; }
    }

    r0 = p0; r1 = p1;
  }

  if (lane < NCLS)                  // lanes 0..9 (lg=0): cnt for nc = l15
    atomicAdd(&out[b * NCLS + lane], cnt * (1.0f / 2048.0f));  // exact dyadic
}

extern "C" void kernel_launch(void* const* d_in, const int* in_sizes, int n_in,
                              void* d_out, int out_size, void* d_ws, size_t ws_size,
                              hipStream_t stream) {
  const float* x  = (const float*)d_in[0];   // [64,2048]
  const float* cw = (const float*)d_in[1];   // [128,1,7]
  const float* W1 = (const float*)d_in[2];   // [256,128]
  const float* W2 = (const float*)d_in[3];   // [10,256]
  float* out = (float*)d_out;                // [64,10]

  char* ws = (char*)d_ws;
  unsigned int*  s1b = (unsigned int*)(ws + S1_OFF);
  signed char*   dp  = (signed char*)(ws + DP_OFF);
  signed char*   dp2 = (signed char*)(ws + DP2_OFF);
  unsigned int*  s2w = (unsigned int*)(ws + S2W_OFF);

  k01_prep<<<dim3(1297), 128, 0, stream>>>(x, cw, W1, W2, s1b, dp, dp2, out);
  k2_mfma_lif2<<<dim3(2, 64, 8), 256, 0, stream>>>(s1b, dp, s2w);
  k34_gemm3_lif3<<<dim3(64, 64), 64, 0, stream>>>(s2w, dp2, out);
  (void)in_sizes; (void)n_in; (void)out_size; (void)ws_size;
}

// Round 12
// 139.229 us; speedup vs baseline: 1.0704x; 1.0704x over previous
//
#include <hip/hip_runtime.h>
#include <stdint.h>

#define T_STEPS 2048
#define BB 64
#define CC 128
#define HH 256
#define NCLS 10

// ws layout:
//   s1b dwords [T][B][4]    : 2048*64*16 = 2097152 B (layer-1 spike BITS:
//                             bit j of dword d -> c = d*32+j)
//   dp  i8   [4][H][C]      : 4*256*128  =  131072 B (W1 digit planes)
//   dp2 i8   [4][16][256]   : 4*16*256   =   16384 B (W2 digit planes, nc padded)
//   s2w dwords [T][B][8]    : 2048*64*32 = 4194304 B (layer-2 spike BITS: bit j
//                             of dword d -> h = d*32+j)
// k2/k34 prefetch overruns land in the region following each buffer (dp after
// s1b; ws slack after s2w) -- loads only, values never consumed.
#define S1_OFF  0
#define DP_OFF  2097152
#define DP2_OFF 2228224
#define S2W_OFF 2244608

typedef int v4i __attribute__((ext_vector_type(4)));
typedef float v4f __attribute__((ext_vector_type(4)));

// 16 spike bits -> 16 i8 bytes (0/1), as one MFMA A-fragment v4i.
__device__ __forceinline__ v4i spread16(unsigned h) {
  v4i a;
  a[0] = (int)((((h      ) & 0xFu) * 0x00204081u) & 0x01010101u);
  a[1] = (int)((((h >> 4 ) & 0xFu) * 0x00204081u) & 0x01010101u);
  a[2] = (int)((((h >> 8 ) & 0xFu) * 0x00204081u) & 0x01010101u);
  a[3] = (int)((((h >> 12) & 0xFu) * 0x00204081u) & 0x01010101u);
  return a;
}

// ---------------- K01: digits + conv/LIF1(bits) + out-zero, one dispatch ------
// blocks 0..1023   : conv1d+LIF1, chunk = bx>>6, b = bx&63 (128 steps, 64 warmup)
//                    x-window (199 floats) staged in LDS once per block [R8: -14us]
// blocks 1024..1279: W1 digit planes, h = bx-1024
// blocks 1280..1295: W2 digit planes, nc = bx-1280 (rows >= NCLS zeroed)
// block  1296      : zero d_out (re-poisoned 0xAA before every call)
__global__ __launch_bounds__(128) void k01_prep(
    const float* __restrict__ x, const float* __restrict__ cw,
    const float* __restrict__ W1, const float* __restrict__ W2,
    unsigned int* __restrict__ s1b, signed char* __restrict__ dp,
    signed char* __restrict__ dp2, float* __restrict__ out) {
  const int bx = blockIdx.x;
  const int tidx = threadIdx.x;
  __shared__ float xs[200];

  if (bx < 1024) {
    const int c = tidx;
    const int wv = tidx >> 6;       // 0..1 -> dwords 2*wv, 2*wv+1
    const int lane = tidx & 63;
    const int b = bx & 63;
    const int t0 = (bx >> 6) * 128;
    const int ts = t0 - 64;

    // stage x[t0-67 .. t0+131] (199 floats; OOB -> 0) -- coalesced, once.
    const float* xb = x + b * 2048;
    const int base = t0 - 67;
    for (int i = tidx; i < 200; i += 128) {
      int l = base + i;
      xs[i] = (l >= 0 && l < 2048) ? xb[l] : 0.0f;
    }
    __syncthreads();

    float w[7];
#pragma unroll
    for (int k = 0; k < 7; ++k) w[k] = cw[c * 7 + k];

    float xw[7];
#pragma unroll
    for (int k = 0; k < 7; ++k) xw[k] = xs[k];   // l = ts+k-3 = base+k

    float v = 0.0f;
#pragma unroll 7
    for (int t = ts; t < t0 + 128; ++t) {
      float u = fmaf(w[0], xw[0],
                fmaf(w[1], xw[1],
                fmaf(w[2], xw[2],
                fmaf(w[3], xw[3],
                fmaf(w[4], xw[4],
                fmaf(w[5], xw[5], w[6] * xw[6]))))));
      v = fmaf(v, 0.5f, u);           // v*0.5 exact -> fmaf == ref's mul-then-add
      bool sp = (v >= 1.0f);
      unsigned long long Bm = __ballot(sp);   // bit i -> c = wv*64 + i
      if (t >= t0 && lane == 0)
        *(unsigned long long*)(s1b + ((size_t)t * BB + b) * 4 + wv * 2) = Bm;
      if (sp) v = 0.0f;
#pragma unroll
      for (int k = 0; k < 6; ++k) xw[k] = xw[k + 1];
      xw[6] = xs[t - t0 + 71];        // l = t+4 = base + (t-t0+71); OOB staged 0
    }
  } else if (bx < 1280) {
    // W1 digits: q = rn(w*2^31), q = d0 + 256*(d1 + 256*(d2 + 256*d3)), exact.
    const int h = bx - 1024;
    const int c = tidx;
    float w = W1[h * CC + c];
    int q = __float2int_rn(w * 2147483648.0f);
#pragma unroll
    for (int d = 0; d < 3; ++d) {
      int dig = (int)(signed char)(q & 0xff);
      dp[d * (HH * CC) + h * CC + c] = (signed char)dig;
      q = (q - dig) >> 8;
    }
    dp[3 * (HH * CC) + h * CC + c] = (signed char)q;
  } else if (bx < 1296) {
    const int nc = bx - 1280;       // 0..15
#pragma unroll
    for (int half = 0; half < 2; ++half) {
      int cc = half * 128 + tidx;
      float w = (nc < NCLS) ? W2[nc * HH + cc] : 0.0f;
      int q = __float2int_rn(w * 2147483648.0f);
#pragma unroll
      for (int d = 0; d < 3; ++d) {
        int dig = (int)(signed char)(q & 0xff);
        dp2[d * (16 * HH) + nc * HH + cc] = (signed char)dig;
        q = (q - dig) >> 8;
      }
      dp2[3 * (16 * HH) + nc * HH + cc] = (signed char)q;
    }
  } else {
#pragma unroll
    for (int i = 0; i < 5; ++i) out[tidx + 128 * i] = 0.0f;   // 640 = 5*128
  }
}

// ---------------- K2: fused MFMA-i8 (s1bits @ W1^T) + LIF2 -> s2 BITS ----------
// [R12: R8 structure + LDS TRANSPOSE replacing the 32-bpermute gather]
// grid (2 hg, 64 b, 8 chunks), block 256 (4 waves); wave owns 32 h
// (n-tiles n=0,1: h = hg*128 + wv*32 + n*16 + l15). t-chunk = 256 steps
// (+64 warmup for chunk>0; exact: decay 2^-64 + hard reset).
// Evidence: VALU cuts neutral (R6), TLP -50% -> +4% (R10), ballot-decouple
// -> +6% (R11); per-pipe sums VALU ~25us + DS ~20us + MFMA ~8us = measured
// 53us -> near-zero pipe overlap, DS never attacked. R12 cuts DS per sub
// from 32 bpermutes to 2 ds_write_b128 + 4 ds_read_b128 via a per-wave
// [32 h][20 t] f32 LDS buffer (stride 20 = 16B-aligned b128; writes 2-way
// bank-free, reads 4-way ~1.58x; same-wave DS is in-order -> no barrier).
// Also kills the 16 nn-select cndmasks. Pack = R8's proven fused LIFSTEP
// (SALU-interlocked literal writelane; R9's raw-ballot-read hazard avoided).
// Per 16-t sub: 16 x mfma_i32_16x16x64_i8 (2n x 2kc x 4 digits), ZERO C on
// first of each chain, exact digit recombine, LDS transpose, in-lane LIF.
__global__ __launch_bounds__(256, 4) void k2_mfma_lif2(
    const unsigned int* __restrict__ s1b, const signed char* __restrict__ dp,
    unsigned int* __restrict__ s2w) {
  const int tid  = threadIdx.x;
  const int lane = tid & 63;
  const int wv   = tid >> 6;        // 0..3
  const int hg   = blockIdx.x;      // 0..1
  const int b    = blockIdx.y;      // 0..63
  const int chunk= blockIdx.z;      // 0..7
  const int t0   = chunk * 256;
  const int nwarm= (chunk == 0) ? 0 : 4;      // warmup sub-chunks (x16 t)
  const int ts   = t0 - nwarm * 16;
  const int l15  = lane & 15;
  const int lg   = lane >> 4;       // 0..3
  const int nn   = lg >> 1;         // this lane's owned n-tile
  const int hb   = hg * 128 + wv * 32;
  const int hw   = (lg & 1) * 16;   // halfword shift within bit-row dword

  // per-wave u-transpose buffer: [32 h][5 v4f] (20 floats, 16B-aligned rows)
  __shared__ v4f tbuf[4 * 32 * 5];  // 10240 B
  const int wb    = wv * 160;                 // wave base (v4f units)
  const int widx0 = wb + l15 * 5 + lg;        // u0 -> row h-idx l15, t-slot lg
  const int widx1 = wb + (16 + l15) * 5 + lg; // u1 -> row 16+l15
  const int ridx  = wb + (nn * 16 + l15) * 5; // lane's h row, slots q=0..3

  // B fragments (verified layout): lane holds k = kc*64 + lg*16 + j.
  v4i Bf[2][4][2];
#pragma unroll
  for (int n = 0; n < 2; ++n)
#pragma unroll
    for (int d = 0; d < 4; ++d)
#pragma unroll
      for (int kc = 0; kc < 2; ++kc)
        Bf[n][d][kc] = *(const v4i*)(dp + d * (HH * CC) +
                                     (hb + n * 16 + l15) * CC + kc * 64 + lg * 16);

  // A bit-rows: lane reads row t = tb + l15 (16B = 128 c-bits), 2-deep prefetch.
  const unsigned int* ap = s1b + ((size_t)(ts + l15) * BB + b) * 4;
  uint4 Ra = *(const uint4*)ap;
  uint4 Pb = *(const uint4*)(ap + 16 * BB * 4);
  const unsigned int* ap2 = ap + 2 * 16 * BB * 4;

  float v = 0.0f;                   // LIF2 state for column (h = hb + nn*16 + l15)
  const v4i ZZ = {0, 0, 0, 0};      // loop-invariant zero C operand

  const int nsub = nwarm + 16;
  for (int s = 0; s < nsub; ++s) {
    const int tb = ts + s * 16;

    // prefetch sub s+2 (overrun past s1b lands in dp region: loads-only)
    uint4 Pc = *(const uint4*)ap2;
    ap2 += 16 * BB * 4;

    // decode this sub's A fragments from bits (same nibble-spread as k34)
    const unsigned w01 = (lg & 2) ? Ra.y : Ra.x;   // kc=0 dword (lg>>1)
    const unsigned w23 = (lg & 2) ? Ra.w : Ra.z;   // kc=1 dword 2+(lg>>1)
    v4i Af0 = spread16((w01 >> hw) & 0xFFFFu);
    v4i Af1 = spread16((w23 >> hw) & 0xFFFFu);

    v4f U0, U1;                     // u[t=lg*4+r][n-tile 0/1, col l15]
#pragma unroll
    for (int n = 0; n < 2; ++n) {
      v4i a0, a1, a2, a3;
      a0 = __builtin_amdgcn_mfma_i32_16x16x64_i8(Af0, Bf[n][0][0], ZZ, 0, 0, 0);
      a1 = __builtin_amdgcn_mfma_i32_16x16x64_i8(Af0, Bf[n][1][0], ZZ, 0, 0, 0);
      a2 = __builtin_amdgcn_mfma_i32_16x16x64_i8(Af0, Bf[n][2][0], ZZ, 0, 0, 0);
      a3 = __builtin_amdgcn_mfma_i32_16x16x64_i8(Af0, Bf[n][3][0], ZZ, 0, 0, 0);
      a0 = __builtin_amdgcn_mfma_i32_16x16x64_i8(Af1, Bf[n][0][1], a0, 0, 0, 0);
      a1 = __builtin_amdgcn_mfma_i32_16x16x64_i8(Af1, Bf[n][1][1], a1, 0, 0, 0);
      a2 = __builtin_amdgcn_mfma_i32_16x16x64_i8(Af1, Bf[n][2][1], a2, 0, 0, 0);
      a3 = __builtin_amdgcn_mfma_i32_16x16x64_i8(Af1, Bf[n][3][1], a3, 0, 0, 0);
#pragma unroll
      for (int r = 0; r < 4; ++r) {
        int hi = a3[r] * 256 + a2[r];             // exact, |.| < 2^24
        int lo = a1[r] * 256 + a0[r];
        float u = fmaf((float)hi, 0x1p-15f, (float)lo * 0x1p-31f);
        if (n == 0) U0[r] = u; else U1[r] = u;
      }
    }

    // LDS transpose: write [h][t] (2 x ds_write_b128), read own h row
    // (4 x ds_read_b128). Same-wave DS in-order; per-wave region, no barrier.
    tbuf[widx0] = U0;
    tbuf[widx1] = U1;
    v4f ua0 = tbuf[ridx + 0];       // t = 0..3
    v4f ua1 = tbuf[ridx + 1];       // t = 4..7
    v4f ua2 = tbuf[ridx + 2];       // t = 8..11
    v4f ua3 = tbuf[ridx + 3];       // t = 12..15

    // in-lane 16-step LIF (R8's proven fused pack): ballot -> SALU pack ->
    // literal-index writelane deposit into lane J (lane J: lg==0, l15==J).
    unsigned sel = 0;
#define LIFSTEP(J, UAJ)                                                    \
    {                                                                      \
      v = fmaf(v, 0.5f, (UAJ));                                            \
      bool sp = (v >= 1.0f);                                               \
      if (sp) v = 0.0f;                                                    \
      unsigned long long Bm = __ballot(sp);                                \
      unsigned pk = (unsigned)(Bm & 0xFFFFull) |                           \
                    ((unsigned)((Bm >> 32) & 0xFFFFull) << 16);            \
      asm("v_writelane_b32 %0, %1, " #J : "+v"(sel) : "s"(pk));            \
    }
    LIFSTEP(0,  ua0[0]) LIFSTEP(1,  ua0[1]) LIFSTEP(2,  ua0[2]) LIFSTEP(3,  ua0[3])
    LIFSTEP(4,  ua1[0]) LIFSTEP(5,  ua1[1]) LIFSTEP(6,  ua1[2]) LIFSTEP(7,  ua1[3])
    LIFSTEP(8,  ua2[0]) LIFSTEP(9,  ua2[1]) LIFSTEP(10, ua2[2]) LIFSTEP(11, ua2[3])
    LIFSTEP(12, ua3[0]) LIFSTEP(13, ua3[1]) LIFSTEP(14, ua3[2]) LIFSTEP(15, ua3[3])
#undef LIFSTEP

    if (s >= nwarm && lg == 0)       // 16 lanes store dword(32 h) for t = tb+l15
      s2w[((size_t)(tb + l15) * BB + b) * 8 + hg * 4 + wv] = sel;

    Ra = Pb; Pb = Pc;
  }
}

// ---------------- K34: fused MFMA-i8 (s2bits @ W2^T) + LIF3 + count ------------
// grid (64 b, 64 chunks), block 64 (1 wave); 4096 waves = 4/SIMD.
// chunk = 32 t = 2 subs (+4 warmup subs, chunk>0). Per sub: load the 16 t-rows'
// 256-bit spike bitmaps (2 dwordx4/lane), nibble-spread decode to i8 A-frags,
// 16 MFMA (4 kc x 4 digits, ZERO C on first of each chain), exact recombine,
// bpermute transpose, in-lane LIF3 + spike count; one atomicAdd per class.
__global__ __launch_bounds__(64, 4) void k34_gemm3_lif3(
    const unsigned int* __restrict__ s2w, const signed char* __restrict__ dp2,
    float* __restrict__ out) {
  const int lane = threadIdx.x;
  const int l15  = lane & 15;
  const int lg   = lane >> 4;
  const int b    = blockIdx.x;      // 0..63
  const int chunk= blockIdx.y;      // 0..63
  const int t0   = chunk * 32;
  const int nwarm= (chunk == 0) ? 0 : 4;
  const int ts   = t0 - nwarm * 16;

  v4i Bf[4][4];                     // [digit][kc]; col = l15 -> nc
#pragma unroll
  for (int d = 0; d < 4; ++d)
#pragma unroll
    for (int kc = 0; kc < 4; ++kc)
      Bf[d][kc] = *(const v4i*)(dp2 + d * (16 * HH) + l15 * HH + kc * 64 + lg * 16);

  // bit-row pointer for t = ts + l15 (row = 8 dwords = 2 uint4)
  const uint4* rp = (const uint4*)s2w + ((size_t)(ts + l15) * BB + b) * 2;
  uint4 r0 = rp[0], r1 = rp[1];
  rp += 16 * BB * 2;

  const int a4 = l15 * 4;
  const int hw = (lg & 1) * 16;     // halfword shift
  float v = 0.0f, cnt = 0.0f;
  const v4i ZZ = {0, 0, 0, 0};      // loop-invariant zero C operand

  const int nsub = nwarm + 2;
  for (int s = 0; s < nsub; ++s) {
    uint4 p0 = rp[0], p1 = rp[1];   // prefetch (overrun past s2w: slack ws)
    rp += 16 * BB * 2;

    unsigned rowd[8] = {r0.x, r0.y, r0.z, r0.w, r1.x, r1.y, r1.z, r1.w};

    v4i a0, a1, a2, a3;
#pragma unroll
    for (int kc = 0; kc < 4; ++kc) {
      unsigned h16 = (rowd[kc * 2 + (lg >> 1)] >> hw) & 0xFFFFu;
      v4i Af = spread16(h16);
      a0 = __builtin_amdgcn_mfma_i32_16x16x64_i8(Af, Bf[0][kc], kc ? a0 : ZZ, 0, 0, 0);
      a1 = __builtin_amdgcn_mfma_i32_16x16x64_i8(Af, Bf[1][kc], kc ? a1 : ZZ, 0, 0, 0);
      a2 = __builtin_amdgcn_mfma_i32_16x16x64_i8(Af, Bf[2][kc], kc ? a2 : ZZ, 0, 0, 0);
      a3 = __builtin_amdgcn_mfma_i32_16x16x64_i8(Af, Bf[3][kc], kc ? a3 : ZZ, 0, 0, 0);
    }

    float u[4];
#pragma unroll
    for (int r = 0; r < 4; ++r) {
      int hi = a3[r] * 256 + a2[r];
      int lo = a1[r] * 256 + a0[r];
      u[r] = fmaf((float)hi, 0x1p-15f, (float)lo * 0x1p-31f);
    }

    float ua[16];
#pragma unroll
    for (int q = 0; q < 4; ++q) {
      const int addr = a4 + q * 64;
#pragma unroll
      for (int r = 0; r < 4; ++r)
        ua[q * 4 + r] = __int_as_float(
            __builtin_amdgcn_ds_bpermute(addr, __float_as_int(u[r])));
    }

    float inc = (s >= nwarm) ? 1.0f : 0.0f;
#pragma unroll
    for (int j = 0; j < 16; ++j) {
      v = fmaf(v, 0.5f, ua[j]);
      bool sp = (v >= 1.0f);
      if (sp) { v = 0.0f; cnt += inc; }
    }

    r0 = p0; r1 = p1;
  }

  if (lane < NCLS)                  // lanes 0..9 (lg=0): cnt for nc = l15
    atomicAdd(&out[b * NCLS + lane], cnt * (1.0f / 2048.0f));  // exact dyadic
}

extern "C" void kernel_launch(void* const* d_in, const int* in_sizes, int n_in,
                              void* d_out, int out_size, void* d_ws, size_t ws_size,
                              hipStream_t stream) {
  const float* x  = (const float*)d_in[0];   // [64,2048]
  const float* cw = (const float*)d_in[1];   // [128,1,7]
  const float* W1 = (const float*)d_in[2];   // [256,128]
  const float* W2 = (const float*)d_in[3];   // [10,256]
  float* out = (float*)d_out;                // [64,10]

  char* ws = (char*)d_ws;
  unsigned int*  s1b = (unsigned int*)(ws + S1_OFF);
  signed char*   dp  = (signed char*)(ws + DP_OFF);
  signed char*   dp2 = (signed char*)(ws + DP2_OFF);
  unsigned int*  s2w = (unsigned int*)(ws + S2W_OFF);

  k01_prep<<<dim3(1297), 128, 0, stream>>>(x, cw, W1, W2, s1b, dp, dp2, out);
  k2_mfma_lif2<<<dim3(2, 64, 8), 256, 0, stream>>>(s1b, dp, s2w);
  k34_gemm3_lif3<<<dim3(64, 64), 64, 0, stream>>>(s2w, dp2, out);
  (void)in_sizes; (void)n_in; (void)out_size; (void)ws_size;
}

// Round 13
// 137.339 us; speedup vs baseline: 1.0851x; 1.0138x over previous
//
#include <hip/hip_runtime.h>
#include <stdint.h>

#define T_STEPS 2048
#define BB 64
#define CC 128
#define HH 256
#define NCLS 10

// ws layout:
//   s1b dwords [T][B][4]    : 2048*64*16 = 2097152 B (layer-1 spike BITS:
//                             bit j of dword d -> c = d*32+j)
//   dp  i8   [4][H][C]      : 4*256*128  =  131072 B (W1 digit planes)
//   dp2 i8   [4][16][256]   : 4*16*256   =   16384 B (W2 digit planes, nc padded)
//   s2w dwords [T][B][8]    : 2048*64*32 = 4194304 B (layer-2 spike BITS: bit j
//                             of dword d -> h = d*32+j)
// k2/k34 prefetch overruns land in the region following each buffer (dp after
// s1b; ws slack after s2w) -- loads only, values never consumed.
#define S1_OFF  0
#define DP_OFF  2097152
#define DP2_OFF 2228224
#define S2W_OFF 2244608

typedef int v4i __attribute__((ext_vector_type(4)));
typedef float v4f __attribute__((ext_vector_type(4)));

// 16 spike bits -> 16 i8 bytes (0/1), as one MFMA A-fragment v4i.
__device__ __forceinline__ v4i spread16(unsigned h) {
  v4i a;
  a[0] = (int)((((h      ) & 0xFu) * 0x00204081u) & 0x01010101u);
  a[1] = (int)((((h >> 4 ) & 0xFu) * 0x00204081u) & 0x01010101u);
  a[2] = (int)((((h >> 8 ) & 0xFu) * 0x00204081u) & 0x01010101u);
  a[3] = (int)((((h >> 12) & 0xFu) * 0x00204081u) & 0x01010101u);
  return a;
}

// ---------------- K01: digits + conv/LIF1(bits) + out-zero, one dispatch ------
// blocks 0..1023   : conv1d+LIF1, chunk = bx>>6, b = bx&63 (128 steps, 64 warmup)
//                    x-window (199 floats) staged in LDS once per block [R8: -14us]
// blocks 1024..1279: W1 digit planes, h = bx-1024
// blocks 1280..1295: W2 digit planes, nc = bx-1280 (rows >= NCLS zeroed)
// block  1296      : zero d_out (re-poisoned 0xAA before every call)
__global__ __launch_bounds__(128) void k01_prep(
    const float* __restrict__ x, const float* __restrict__ cw,
    const float* __restrict__ W1, const float* __restrict__ W2,
    unsigned int* __restrict__ s1b, signed char* __restrict__ dp,
    signed char* __restrict__ dp2, float* __restrict__ out) {
  const int bx = blockIdx.x;
  const int tidx = threadIdx.x;
  __shared__ float xs[200];

  if (bx < 1024) {
    const int c = tidx;
    const int wv = tidx >> 6;       // 0..1 -> dwords 2*wv, 2*wv+1
    const int lane = tidx & 63;
    const int b = bx & 63;
    const int t0 = (bx >> 6) * 128;
    const int ts = t0 - 64;

    // stage x[t0-67 .. t0+131] (199 floats; OOB -> 0) -- coalesced, once.
    const float* xb = x + b * 2048;
    const int base = t0 - 67;
    for (int i = tidx; i < 200; i += 128) {
      int l = base + i;
      xs[i] = (l >= 0 && l < 2048) ? xb[l] : 0.0f;
    }
    __syncthreads();

    float w[7];
#pragma unroll
    for (int k = 0; k < 7; ++k) w[k] = cw[c * 7 + k];

    float xw[7];
#pragma unroll
    for (int k = 0; k < 7; ++k) xw[k] = xs[k];   // l = ts+k-3 = base+k

    float v = 0.0f;
#pragma unroll 7
    for (int t = ts; t < t0 + 128; ++t) {
      float u = fmaf(w[0], xw[0],
                fmaf(w[1], xw[1],
                fmaf(w[2], xw[2],
                fmaf(w[3], xw[3],
                fmaf(w[4], xw[4],
                fmaf(w[5], xw[5], w[6] * xw[6]))))));
      v = fmaf(v, 0.5f, u);           // v*0.5 exact -> fmaf == ref's mul-then-add
      bool sp = (v >= 1.0f);
      unsigned long long Bm = __ballot(sp);   // bit i -> c = wv*64 + i
      if (t >= t0 && lane == 0)
        *(unsigned long long*)(s1b + ((size_t)t * BB + b) * 4 + wv * 2) = Bm;
      if (sp) v = 0.0f;
#pragma unroll
      for (int k = 0; k < 6; ++k) xw[k] = xw[k + 1];
      xw[6] = xs[t - t0 + 71];        // l = t+4 = base + (t-t0+71); OOB staged 0
    }
  } else if (bx < 1280) {
    // W1 digits: q = rn(w*2^31), q = d0 + 256*(d1 + 256*(d2 + 256*d3)), exact.
    const int h = bx - 1024;
    const int c = tidx;
    float w = W1[h * CC + c];
    int q = __float2int_rn(w * 2147483648.0f);
#pragma unroll
    for (int d = 0; d < 3; ++d) {
      int dig = (int)(signed char)(q & 0xff);
      dp[d * (HH * CC) + h * CC + c] = (signed char)dig;
      q = (q - dig) >> 8;
    }
    dp[3 * (HH * CC) + h * CC + c] = (signed char)q;
  } else if (bx < 1296) {
    const int nc = bx - 1280;       // 0..15
#pragma unroll
    for (int half = 0; half < 2; ++half) {
      int cc = half * 128 + tidx;
      float w = (nc < NCLS) ? W2[nc * HH + cc] : 0.0f;
      int q = __float2int_rn(w * 2147483648.0f);
#pragma unroll
      for (int d = 0; d < 3; ++d) {
        int dig = (int)(signed char)(q & 0xff);
        dp2[d * (16 * HH) + nc * HH + cc] = (signed char)dig;
        q = (q - dig) >> 8;
      }
      dp2[3 * (16 * HH) + nc * HH + cc] = (signed char)q;
    }
  } else {
#pragma unroll
    for (int i = 0; i < 5; ++i) out[tidx + 128 * i] = 0.0f;   // 640 = 5*128
  }
}

// ---------------- K2: fused MFMA-i8 (s1bits @ W1^T) + LIF2 -> s2 BITS ----------
// [R13: R12 + 1-deep SOFTWARE-PIPELINE SKEW] grid (2 hg, 64 b, 8 chunks),
// block 256 (4 waves); wave owns 32 h (n-tiles n=0,1: h = hg*128+wv*32+n*16+l15).
// t-chunk = 256 steps (+64 warmup for chunk>0; exact: decay 2^-64 + reset).
// R12 (-13%) proved the per-sub phase chain decode->MFMA->recombine->LDS->LIF
// was serially chained with no pipe overlap. R13 skews one sub: loop body =
// {LDS-read ua for sub s-1} -> {prefetch/decode/MFMA/recombine/LDS-write sub s}
// -> {LIF sub s-1}. The serial ~190cy LIF recurrence now interleaves with the
// NEXT sub's independent MFMA+VALU issue. tbuf parity-doubled (2 x 10KB) so
// read(s-1) and write(s) hit distinct regions; same-wave DS is in-order ->
// still no barrier. All primitives byte-identical to R12 (verified absmax 0).
__global__ __launch_bounds__(256, 4) void k2_mfma_lif2(
    const unsigned int* __restrict__ s1b, const signed char* __restrict__ dp,
    unsigned int* __restrict__ s2w) {
  const int tid  = threadIdx.x;
  const int lane = tid & 63;
  const int wv   = tid >> 6;        // 0..3
  const int hg   = blockIdx.x;      // 0..1
  const int b    = blockIdx.y;      // 0..63
  const int chunk= blockIdx.z;      // 0..7
  const int t0   = chunk * 256;
  const int nwarm= (chunk == 0) ? 0 : 4;      // warmup sub-chunks (x16 t)
  const int ts   = t0 - nwarm * 16;
  const int l15  = lane & 15;
  const int lg   = lane >> 4;       // 0..3
  const int nn   = lg >> 1;         // this lane's owned n-tile
  const int hb   = hg * 128 + wv * 32;
  const int hw   = (lg & 1) * 16;   // halfword shift within bit-row dword

  // per-wave u-transpose buffer, parity-doubled:
  // [2 parity][4 wave][32 h][5 v4f] (stride 20 floats = 16B-aligned rows)
  __shared__ v4f tbuf[2 * 4 * 32 * 5];        // 20480 B
  const int wb    = wv * 160;                 // wave base within parity (v4f)
  const int widx0 = wb + l15 * 5 + lg;        // u0 -> row h-idx l15, t-slot lg
  const int widx1 = wb + (16 + l15) * 5 + lg; // u1 -> row 16+l15
  const int ridx  = wb + (nn * 16 + l15) * 5; // lane's h row, slots 0..3

  // B fragments (verified layout): lane holds k = kc*64 + lg*16 + j.
  v4i Bf[2][4][2];
#pragma unroll
  for (int n = 0; n < 2; ++n)
#pragma unroll
    for (int d = 0; d < 4; ++d)
#pragma unroll
      for (int kc = 0; kc < 2; ++kc)
        Bf[n][d][kc] = *(const v4i*)(dp + d * (HH * CC) +
                                     (hb + n * 16 + l15) * CC + kc * 64 + lg * 16);

  // A bit-rows: lane reads row t = tb + l15 (16B = 128 c-bits), 2-deep prefetch.
  const unsigned int* ap = s1b + ((size_t)(ts + l15) * BB + b) * 4;
  uint4 Ra = *(const uint4*)ap;
  uint4 Pb = *(const uint4*)(ap + 16 * BB * 4);
  const unsigned int* ap2 = ap + 2 * 16 * BB * 4;

  float v = 0.0f;                   // LIF2 state for column (h = hb + nn*16 + l15)
  const v4i ZZ = {0, 0, 0, 0};      // loop-invariant zero C operand

  // stage sub s (decode Ra -> 16 MFMA -> recombine -> tbuf[par])
  auto stage = [&](int par) {
    const unsigned w01 = (lg & 2) ? Ra.y : Ra.x;   // kc=0 dword (lg>>1)
    const unsigned w23 = (lg & 2) ? Ra.w : Ra.z;   // kc=1 dword 2+(lg>>1)
    v4i Af0 = spread16((w01 >> hw) & 0xFFFFu);
    v4i Af1 = spread16((w23 >> hw) & 0xFFFFu);
    v4f U0, U1;                     // u[t=lg*4+r][n-tile 0/1, col l15]
#pragma unroll
    for (int n = 0; n < 2; ++n) {
      v4i a0, a1, a2, a3;
      a0 = __builtin_amdgcn_mfma_i32_16x16x64_i8(Af0, Bf[n][0][0], ZZ, 0, 0, 0);
      a1 = __builtin_amdgcn_mfma_i32_16x16x64_i8(Af0, Bf[n][1][0], ZZ, 0, 0, 0);
      a2 = __builtin_amdgcn_mfma_i32_16x16x64_i8(Af0, Bf[n][2][0], ZZ, 0, 0, 0);
      a3 = __builtin_amdgcn_mfma_i32_16x16x64_i8(Af0, Bf[n][3][0], ZZ, 0, 0, 0);
      a0 = __builtin_amdgcn_mfma_i32_16x16x64_i8(Af1, Bf[n][0][1], a0, 0, 0, 0);
      a1 = __builtin_amdgcn_mfma_i32_16x16x64_i8(Af1, Bf[n][1][1], a1, 0, 0, 0);
      a2 = __builtin_amdgcn_mfma_i32_16x16x64_i8(Af1, Bf[n][2][1], a2, 0, 0, 0);
      a3 = __builtin_amdgcn_mfma_i32_16x16x64_i8(Af1, Bf[n][3][1], a3, 0, 0, 0);
#pragma unroll
      for (int r = 0; r < 4; ++r) {
        int hi = a3[r] * 256 + a2[r];             // exact, |.| < 2^24
        int lo = a1[r] * 256 + a0[r];
        float u = fmaf((float)hi, 0x1p-15f, (float)lo * 0x1p-31f);
        if (n == 0) U0[r] = u; else U1[r] = u;
      }
    }
    tbuf[par * 640 + widx0] = U0;   // 2 x ds_write_b128, 2-way bank-free
    tbuf[par * 640 + widx1] = U1;
  };

  const int nsub = nwarm + 16;

  // prologue: stage sub 0 into parity 0, advance prefetch pipe
  stage(0);
  {
    uint4 Pc0 = *(const uint4*)ap2;             // sub 2
    ap2 += 16 * BB * 4;
    Ra = Pb; Pb = Pc0;
  }

  for (int s = 1; s < nsub; ++s) {
    // (1) read ua for sub s-1 (parity (s-1)&1; written last iteration)
    const int rbase = ((s - 1) & 1) * 640 + ridx;
    v4f ua0 = tbuf[rbase + 0];
    v4f ua1 = tbuf[rbase + 1];
    v4f ua2 = tbuf[rbase + 2];
    v4f ua3 = tbuf[rbase + 3];

    // (2) prefetch sub s+2 (overrun lands in dp region: loads-only) + stage s
    uint4 Pc = *(const uint4*)ap2;
    ap2 += 16 * BB * 4;
    stage(s & 1);
    Ra = Pb; Pb = Pc;

    // (3) in-lane 16-step LIF for sub s-1 (R8's proven fused pack: ballot ->
    // SALU pack -> literal-index writelane into lane J; lane J: lg==0,l15==J)
    unsigned sel = 0;
#define LIFSTEP(J, UAJ)                                                    \
    {                                                                      \
      v = fmaf(v, 0.5f, (UAJ));                                            \
      bool sp = (v >= 1.0f);                                               \
      if (sp) v = 0.0f;                                                    \
      unsigned long long Bm = __ballot(sp);                                \
      unsigned pk = (unsigned)(Bm & 0xFFFFull) |                           \
                    ((unsigned)((Bm >> 32) & 0xFFFFull) << 16);            \
      asm("v_writelane_b32 %0, %1, " #J : "+v"(sel) : "s"(pk));            \
    }
    LIFSTEP(0,  ua0[0]) LIFSTEP(1,  ua0[1]) LIFSTEP(2,  ua0[2]) LIFSTEP(3,  ua0[3])
    LIFSTEP(4,  ua1[0]) LIFSTEP(5,  ua1[1]) LIFSTEP(6,  ua1[2]) LIFSTEP(7,  ua1[3])
    LIFSTEP(8,  ua2[0]) LIFSTEP(9,  ua2[1]) LIFSTEP(10, ua2[2]) LIFSTEP(11, ua2[3])
    LIFSTEP(12, ua3[0]) LIFSTEP(13, ua3[1]) LIFSTEP(14, ua3[2]) LIFSTEP(15, ua3[3])

    const int tbp = ts + (s - 1) * 16;
    if (s - 1 >= nwarm && lg == 0)  // 16 lanes store dword(32 h) for t = tbp+l15
      s2w[((size_t)(tbp + l15) * BB + b) * 8 + hg * 4 + wv] = sel;
  }

  // epilogue: LIF for the last staged sub (always >= nwarm)
  {
    const int rbase = ((nsub - 1) & 1) * 640 + ridx;
    v4f ua0 = tbuf[rbase + 0];
    v4f ua1 = tbuf[rbase + 1];
    v4f ua2 = tbuf[rbase + 2];
    v4f ua3 = tbuf[rbase + 3];
    unsigned sel = 0;
    LIFSTEP(0,  ua0[0]) LIFSTEP(1,  ua0[1]) LIFSTEP(2,  ua0[2]) LIFSTEP(3,  ua0[3])
    LIFSTEP(4,  ua1[0]) LIFSTEP(5,  ua1[1]) LIFSTEP(6,  ua1[2]) LIFSTEP(7,  ua1[3])
    LIFSTEP(8,  ua2[0]) LIFSTEP(9,  ua2[1]) LIFSTEP(10, ua2[2]) LIFSTEP(11, ua2[3])
    LIFSTEP(12, ua3[0]) LIFSTEP(13, ua3[1]) LIFSTEP(14, ua3[2]) LIFSTEP(15, ua3[3])
#undef LIFSTEP
    const int tbp = ts + (nsub - 1) * 16;
    if (lg == 0)
      s2w[((size_t)(tbp + l15) * BB + b) * 8 + hg * 4 + wv] = sel;
  }
}

// ---------------- K34: fused MFMA-i8 (s2bits @ W2^T) + LIF3 + count ------------
// grid (64 b, 64 chunks), block 64 (1 wave); 4096 waves = 4/SIMD.
// chunk = 32 t = 2 subs (+4 warmup subs, chunk>0). Per sub: load the 16 t-rows'
// 256-bit spike bitmaps (2 dwordx4/lane), nibble-spread decode to i8 A-frags,
// 16 MFMA (4 kc x 4 digits, ZERO C on first of each chain), exact recombine,
// bpermute transpose, in-lane LIF3 + spike count; one atomicAdd per class.
__global__ __launch_bounds__(64, 4) void k34_gemm3_lif3(
    const unsigned int* __restrict__ s2w, const signed char* __restrict__ dp2,
    float* __restrict__ out) {
  const int lane = threadIdx.x;
  const int l15  = lane & 15;
  const int lg   = lane >> 4;
  const int b    = blockIdx.x;      // 0..63
  const int chunk= blockIdx.y;      // 0..63
  const int t0   = chunk * 32;
  const int nwarm= (chunk == 0) ? 0 : 4;
  const int ts   = t0 - nwarm * 16;

  v4i Bf[4][4];                     // [digit][kc]; col = l15 -> nc
#pragma unroll
  for (int d = 0; d < 4; ++d)
#pragma unroll
    for (int kc = 0; kc < 4; ++kc)
      Bf[d][kc] = *(const v4i*)(dp2 + d * (16 * HH) + l15 * HH + kc * 64 + lg * 16);

  // bit-row pointer for t = ts + l15 (row = 8 dwords = 2 uint4)
  const uint4* rp = (const uint4*)s2w + ((size_t)(ts + l15) * BB + b) * 2;
  uint4 r0 = rp[0], r1 = rp[1];
  rp += 16 * BB * 2;

  const int a4 = l15 * 4;
  const int hw = (lg & 1) * 16;     // halfword shift
  float v = 0.0f, cnt = 0.0f;
  const v4i ZZ = {0, 0, 0, 0};      // loop-invariant zero C operand

  const int nsub = nwarm + 2;
  for (int s = 0; s < nsub; ++s) {
    uint4 p0 = rp[0], p1 = rp[1];   // prefetch (overrun past s2w: slack ws)
    rp += 16 * BB * 2;

    unsigned rowd[8] = {r0.x, r0.y, r0.z, r0.w, r1.x, r1.y, r1.z, r1.w};

    v4i a0, a1, a2, a3;
#pragma unroll
    for (int kc = 0; kc < 4; ++kc) {
      unsigned h16 = (rowd[kc * 2 + (lg >> 1)] >> hw) & 0xFFFFu;
      v4i Af = spread16(h16);
      a0 = __builtin_amdgcn_mfma_i32_16x16x64_i8(Af, Bf[0][kc], kc ? a0 : ZZ, 0, 0, 0);
      a1 = __builtin_amdgcn_mfma_i32_16x16x64_i8(Af, Bf[1][kc], kc ? a1 : ZZ, 0, 0, 0);
      a2 = __builtin_amdgcn_mfma_i32_16x16x64_i8(Af, Bf[2][kc], kc ? a2 : ZZ, 0, 0, 0);
      a3 = __builtin_amdgcn_mfma_i32_16x16x64_i8(Af, Bf[3][kc], kc ? a3 : ZZ, 0, 0, 0);
    }

    float u[4];
#pragma unroll
    for (int r = 0; r < 4; ++r) {
      int hi = a3[r] * 256 + a2[r];
      int lo = a1[r] * 256 + a0[r];
      u[r] = fmaf((float)hi, 0x1p-15f, (float)lo * 0x1p-31f);
    }

    float ua[16];
#pragma unroll
    for (int q = 0; q < 4; ++q) {
      const int addr = a4 + q * 64;
#pragma unroll
      for (int r = 0; r < 4; ++r)
        ua[q * 4 + r] = __int_as_float(
            __builtin_amdgcn_ds_bpermute(addr, __float_as_int(u[r])));
    }

    float inc = (s >= nwarm) ? 1.0f : 0.0f;
#pragma unroll
    for (int j = 0; j < 16; ++j) {
      v = fmaf(v, 0.5f, ua[j]);
      bool sp = (v >= 1.0f);
      if (sp) { v = 0.0f; cnt += inc; }
    }

    r0 = p0; r1 = p1;
  }

  if (lane < NCLS)                  // lanes 0..9 (lg=0): cnt for nc = l15
    atomicAdd(&out[b * NCLS + lane], cnt * (1.0f / 2048.0f));  // exact dyadic
}

extern "C" void kernel_launch(void* const* d_in, const int* in_sizes, int n_in,
                              void* d_out, int out_size, void* d_ws, size_t ws_size,
                              hipStream_t stream) {
  const float* x  = (const float*)d_in[0];   // [64,2048]
  const float* cw = (const float*)d_in[1];   // [128,1,7]
  const float* W1 = (const float*)d_in[2];   // [256,128]
  const float* W2 = (const float*)d_in[3];   // [10,256]
  float* out = (float*)d_out;                // [64,10]

  char* ws = (char*)d_ws;
  unsigned int*  s1b = (unsigned int*)(ws + S1_OFF);
  signed char*   dp  = (signed char*)(ws + DP_OFF);
  signed char*   dp2 = (signed char*)(ws + DP2_OFF);
  unsigned int*  s2w = (unsigned int*)(ws + S2W_OFF);

  k01_prep<<<dim3(1297), 128, 0, stream>>>(x, cw, W1, W2, s1b, dp, dp2, out);
  k2_mfma_lif2<<<dim3(2, 64, 8), 256, 0, stream>>>(s1b, dp, s2w);
  k34_gemm3_lif3<<<dim3(64, 64), 64, 0, stream>>>(s2w, dp2, out);
  (void)in_sizes; (void)n_in; (void)out_size; (void)ws_size;
}